// Round 1
// baseline (1470.440 us; speedup 1.0000x reference)
//
#include <hip/hip_runtime.h>
#include <math.h>

#define NN 32768
#define NE 262144
#define CD 128
#define NH 8
#define NT 8
#define NR 8

// ---------------- workspace layout (bytes) ----------------
// Wkf    @ 0         524288
// Wvf    @ 524288    524288
// bkf    @ 1048576   4096
// bvf    @ 1052672   4096
// den    @ 1056768   NN*NH*4   = 1048576
// num    @ 2105344   NN*CD*4   = 16777216
// cnt    @ 18882560  NN*4      = 131072
// eperm  @ 19013632  NE*4      = 1048576
// nperm  @ 20062208  NN*4      = 131072
// ectr   @ 20193280  64 ints  (0..7 cnt, 8..16 base, 17..25 ptb, 26..33 cursor)
// nctr   @ 20193536  64 ints
// total ~19.3 MB

__global__ void zero_f(float* __restrict__ p, int n) {
    int i = blockIdx.x * blockDim.x + threadIdx.x;
    int stride = gridDim.x * blockDim.x;
    for (; i < n; i += stride) p[i] = 0.f;
}

__global__ void zero_i(int* __restrict__ p, int n) {
    int i = blockIdx.x * blockDim.x + threadIdx.x;
    if (i < n) p[i] = 0;
}

// fuse relation transforms into k/v weights & biases
__global__ void fuse_weights(const float* __restrict__ Wk, const float* __restrict__ bk,
                             const float* __restrict__ Wv, const float* __restrict__ bv,
                             const float* __restrict__ Aatt, const float* __restrict__ Amsg,
                             float* __restrict__ Wkf, float* __restrict__ bkf,
                             float* __restrict__ Wvf, float* __restrict__ bvf) {
    const int WCNT = NR * CD * CD;  // 131072
    int idx = blockIdx.x * 256 + threadIdx.x;
    if (idx < 2 * WCNT) {
        int which = (idx >= WCNT) ? 1 : 0;
        int o = idx - which * WCNT;
        const float* W = which ? Wv : Wk;
        const float* A = which ? Amsg : Aatt;
        int t = o >> 14;
        int rem = o & 16383;
        int i = rem >> 7;
        int c = rem & 127;
        int h = c >> 4, j = c & 15;
        const float* wrow = W + ((t * CD + i) * CD + h * 16);
        const float* acol = A + (t * NH + h) * 256 + j;
        float s = 0.f;
#pragma unroll
        for (int d = 0; d < 16; ++d) s += wrow[d] * acol[d * 16];
        (which ? Wvf : Wkf)[o] = s;
    } else {
        int o2 = idx - 2 * WCNT;
        if (o2 < 2 * NR * CD) {
            int which = (o2 >= NR * CD) ? 1 : 0;
            int o = o2 - which * NR * CD;
            const float* B = which ? bv : bk;
            const float* A = which ? Amsg : Aatt;
            int t = o >> 7; int c = o & 127; int h = c >> 4; int j = c & 15;
            const float* brow = B + t * CD + h * 16;
            const float* acol = A + (t * NH + h) * 256 + j;
            float s = 0.f;
#pragma unroll
            for (int d = 0; d < 16; ++d) s += brow[d] * acol[d * 16];
            (which ? bvf : bkf)[o] = s;
        }
    }
}

__global__ void hist_kernel(const int* __restrict__ lab, int n, int* __restrict__ ctr) {
    __shared__ int lh[8];
    if (threadIdx.x < 8) lh[threadIdx.x] = 0;
    __syncthreads();
    int i = blockIdx.x * 256 + threadIdx.x;
    if (i < n) atomicAdd(&lh[lab[i]], 1);
    __syncthreads();
    if (threadIdx.x < 8 && lh[threadIdx.x]) atomicAdd(&ctr[threadIdx.x], lh[threadIdx.x]);
}

__global__ void scan_buckets(int* ectr, int* nctr) {
    int* c = nullptr;
    if (threadIdx.x == 0) c = ectr;
    else if (threadIdx.x == 1) c = nctr;
    if (c) {
        int acc = 0, ptb = 0;
        c[8] = 0; c[17] = 0;
        for (int u = 0; u < 8; ++u) {
            acc += c[u];  c[9 + u] = acc;
            ptb += (c[u] + 63) >> 6;  c[18 + u] = ptb;
            c[26 + u] = 0;
        }
    }
}

__global__ void scatter_kernel(const int* __restrict__ lab, int n,
                               int* __restrict__ ctr, int* __restrict__ perm) {
    __shared__ int lh[8];
    __shared__ int lbase[8];
    if (threadIdx.x < 8) lh[threadIdx.x] = 0;
    __syncthreads();
    int i = blockIdx.x * 256 + threadIdx.x;
    int t = 0, lpos = 0;
    bool v = (i < n);
    if (v) { t = lab[i]; lpos = atomicAdd(&lh[t], 1); }
    __syncthreads();
    if (threadIdx.x < 8)
        lbase[threadIdx.x] = lh[threadIdx.x] ? atomicAdd(&ctr[26 + threadIdx.x], lh[threadIdx.x]) : 0;
    __syncthreads();
    if (v) perm[ctr[8 + t] + lbase[t] + lpos] = i;
}

// 64(M) x 128(N) x 128(K) fp32 tile GEMM; 256 threads as 16x16, micro-tile 4x8
__device__ __forceinline__ void gemm_tile(const float (*__restrict__ SA)[129],
                                          const float (*__restrict__ SW)[128],
                                          int ty, int tx, float acc[4][8]) {
#pragma unroll 8
    for (int k = 0; k < 128; ++k) {
        float a[4];
#pragma unroll
        for (int i = 0; i < 4; ++i) a[i] = SA[4 * ty + i][k];
        float4 b0 = *(const float4*)(&SW[k][8 * tx]);
        float4 b1 = *(const float4*)(&SW[k][8 * tx + 4]);
        float bb[8] = {b0.x, b0.y, b0.z, b0.w, b1.x, b1.y, b1.z, b1.w};
#pragma unroll
        for (int i = 0; i < 4; ++i)
#pragma unroll
            for (int j = 0; j < 8; ++j)
                acc[i][j] += a[i] * bb[j];
    }
}

__launch_bounds__(256, 1)
__global__ void edge_kernel(const float* __restrict__ x,
                            const int* __restrict__ src, const int* __restrict__ dst,
                            const float* __restrict__ Wq, const float* __restrict__ bq,
                            const float* __restrict__ Wkf, const float* __restrict__ bkf,
                            const float* __restrict__ Wvf, const float* __restrict__ bvf,
                            const float* __restrict__ pri,
                            const int* __restrict__ ectr, const int* __restrict__ eperm,
                            float* __restrict__ den, float* __restrict__ num,
                            int* __restrict__ cnt) {
    __shared__ float sFS[64][129];
    __shared__ float sFD[64][129];   // later reused to hold Q
    __shared__ float sW[128][128];
    __shared__ float sEX[64][9];
    __shared__ int sSrc[64], sDst[64], sVal[64];

    const int tid = threadIdx.x;
    const int tx = tid & 15, ty = tid >> 4;
    const int b = blockIdx.x;

    int t = -1, lt = 0;
#pragma unroll
    for (int u = 0; u < NR; ++u) {
        int p0 = ectr[17 + u], p1 = ectr[18 + u];
        if (b >= p0 && b < p1) { t = u; lt = b - p0; }
    }
    if (t < 0) return;
    const int base = ectr[8 + t];
    const int sz = ectr[9 + t] - base;
    const int start = lt * 64;

    if (tid < 64) {
        int idx = start + tid;
        int e = (idx < sz) ? eperm[base + idx] : -1;
        sVal[tid] = (e >= 0) ? 1 : 0;
        sSrc[tid] = (e >= 0) ? src[e] : 0;
        sDst[tid] = (e >= 0) ? dst[e] : 0;
    }
    __syncthreads();

    // gather fs/fd rows (coalesced 512B per wave per row-half), stage Wq
    {
        const int cc = tid & 127;
        const int eh = tid >> 7;
        for (int e2 = 0; e2 < 64; e2 += 2) {
            int e = e2 + eh;
            sFS[e][cc] = x[sSrc[e] * CD + cc];
            sFD[e][cc] = x[sDst[e] * CD + cc];
        }
        const float4* gw = (const float4*)(Wq + t * CD * CD);
        float4* lw = (float4*)(&sW[0][0]);
        for (int q = tid; q < CD * CD / 4; q += 256) lw[q] = gw[q];
    }
    __syncthreads();

    float acc[4][8];
    // GEMM A: Q = fd @ Wq + bq
    {
#pragma unroll
        for (int j = 0; j < 8; ++j) {
            float bj = bq[t * CD + 8 * tx + j];
#pragma unroll
            for (int i = 0; i < 4; ++i) acc[i][j] = bj;
        }
        gemm_tile(sFD, sW, ty, tx, acc);
    }
    __syncthreads();
    // park Q into sFD (done reading fd), stage Wk'
#pragma unroll
    for (int i = 0; i < 4; ++i)
#pragma unroll
        for (int j = 0; j < 8; ++j)
            sFD[4 * ty + i][8 * tx + j] = acc[i][j];
    {
        const float4* gw = (const float4*)(Wkf + t * CD * CD);
        float4* lw = (float4*)(&sW[0][0]);
        for (int q = tid; q < CD * CD / 4; q += 256) lw[q] = gw[q];
    }
    __syncthreads();

    // GEMM B: KT = fs @ Wk' + bk'
    {
#pragma unroll
        for (int j = 0; j < 8; ++j) {
            float bj = bkf[t * CD + 8 * tx + j];
#pragma unroll
            for (int i = 0; i < 4; ++i) acc[i][j] = bj;
        }
        gemm_tile(sFS, sW, ty, tx, acc);
    }
    // att -> ex -> den atomics (pair of tx lanes covers one head's 16 dims)
    {
        const int h = tx >> 1;
        const float ph = pri[t * NH + h] * 0.25f;
#pragma unroll
        for (int i = 0; i < 4; ++i) {
            int e = 4 * ty + i;
            float p = 0.f;
#pragma unroll
            for (int j = 0; j < 8; ++j) p += acc[i][j] * sFD[e][8 * tx + j];
            p += __shfl_xor(p, 1);
            if (((tx & 1) == 0) && sVal[e]) {
                float ex = expf(p * ph);
                sEX[e][h] = ex;
                atomicAdd(&den[sDst[e] * NH + h], ex);
            }
        }
    }
    if (tid < 64 && sVal[tid]) atomicAdd(&cnt[sDst[tid]], 1);
    __syncthreads();
    // stage Wv'
    {
        const float4* gw = (const float4*)(Wvf + t * CD * CD);
        float4* lw = (float4*)(&sW[0][0]);
        for (int q = tid; q < CD * CD / 4; q += 256) lw[q] = gw[q];
    }
    __syncthreads();
    // GEMM C: VT = fs @ Wv' + bv'; scatter ex*vt into num
    {
#pragma unroll
        for (int j = 0; j < 8; ++j) {
            float bj = bvf[t * CD + 8 * tx + j];
#pragma unroll
            for (int i = 0; i < 4; ++i) acc[i][j] = bj;
        }
        gemm_tile(sFS, sW, ty, tx, acc);
        const int h = tx >> 1;
#pragma unroll
        for (int i = 0; i < 4; ++i) {
            int e = 4 * ty + i;
            if (!sVal[e]) continue;
            float ex = sEX[e][h];
            float* np = num + (long)sDst[e] * CD + 8 * tx;
#pragma unroll
            for (int j = 0; j < 8; ++j) atomicAdd(&np[j], ex * acc[i][j]);
        }
    }
}

__launch_bounds__(256, 1)
__global__ void node_kernel(const float* __restrict__ x,
                            const float* __restrict__ Wa, const float* __restrict__ ba,
                            const float* __restrict__ skip, const float* __restrict__ gamma,
                            const float* __restrict__ beta,
                            const int* __restrict__ nctr, const int* __restrict__ nperm,
                            const float* __restrict__ den, const float* __restrict__ num,
                            const int* __restrict__ cnt,
                            float* __restrict__ out) {
    __shared__ float sX0[64][129];
    __shared__ float sW[128][128];
    __shared__ int sNode[64], sVal[64];

    const int tid = threadIdx.x;
    const int tx = tid & 15, ty = tid >> 4;
    const int b = blockIdx.x;

    int t = -1, lt = 0;
#pragma unroll
    for (int u = 0; u < NT; ++u) {
        int p0 = nctr[17 + u], p1 = nctr[18 + u];
        if (b >= p0 && b < p1) { t = u; lt = b - p0; }
    }
    if (t < 0) return;
    const int base = nctr[8 + t];
    const int sz = nctr[9 + t] - base;
    const int start = lt * 64;

    if (tid < 64) {
        int idx = start + tid;
        int n = (idx < sz) ? nperm[base + idx] : -1;
        sVal[tid] = (n >= 0) ? 1 : 0;
        sNode[tid] = (n >= 0) ? n : 0;
    }
    __syncthreads();

    // build x0 = num / (den * cnt) (0 if isolated); stage Wa
    {
        const int cc = tid & 127;
        const int eh = tid >> 7;
        for (int e2 = 0; e2 < 64; e2 += 2) {
            int e = e2 + eh;
            int n = sNode[e];
            int ct = cnt[n];
            float v = 0.f;
            if (ct > 0) v = num[(long)n * CD + cc] / (den[n * NH + (cc >> 4)] * (float)ct);
            sX0[e][cc] = v;
        }
        const float4* gw = (const float4*)(Wa + t * CD * CD);
        float4* lw = (float4*)(&sW[0][0]);
        for (int q = tid; q < CD * CD / 4; q += 256) lw[q] = gw[q];
    }
    __syncthreads();

    float acc[4][8];
#pragma unroll
    for (int j = 0; j < 8; ++j) {
        float bj = ba[t * CD + 8 * tx + j];
#pragma unroll
        for (int i = 0; i < 4; ++i) acc[i][j] = bj;
    }
    gemm_tile(sX0, sW, ty, tx, acc);

    // epilogue: gated residual + type-indexed LayerNorm
    const float alpha = 1.f / (1.f + expf(-skip[t]));
    const float oma = 1.f - alpha;
    float g[8], be[8];
#pragma unroll
    for (int j = 0; j < 8; ++j) {
        g[j] = gamma[t * CD + 8 * tx + j];
        be[j] = beta[t * CD + 8 * tx + j];
    }
#pragma unroll
    for (int i = 0; i < 4; ++i) {
        int e = 4 * ty + i;
        int n = sNode[e];
        const float* xr = x + (long)n * CD + 8 * tx;
        float o[8];
        float s1 = 0.f, s2 = 0.f;
#pragma unroll
        for (int j = 0; j < 8; ++j) {
            o[j] = acc[i][j] * alpha + xr[j] * oma;
            s1 += o[j];
            s2 += o[j] * o[j];
        }
#pragma unroll
        for (int m = 1; m < 16; m <<= 1) {
            s1 += __shfl_xor(s1, m);
            s2 += __shfl_xor(s2, m);
        }
        float mu = s1 * (1.f / 128.f);
        float var = s2 * (1.f / 128.f) - mu * mu;
        float rs = rsqrtf(var + 1e-5f);
        if (sVal[e]) {
            float* op = out + (long)n * CD + 8 * tx;
#pragma unroll
            for (int j = 0; j < 8; ++j) op[j] = (o[j] - mu) * rs * g[j] + be[j];
        }
    }
}

extern "C" void kernel_launch(void* const* d_in, const int* in_sizes, int n_in,
                              void* d_out, int out_size, void* d_ws, size_t ws_size,
                              hipStream_t stream) {
    const float* x        = (const float*)d_in[0];
    const int*   type_id  = (const int*)d_in[1];
    const int*   edge_idx = (const int*)d_in[2];
    const int*   edge_attr= (const int*)d_in[3];
    const float* Wk   = (const float*)d_in[4];
    const float* bk   = (const float*)d_in[5];
    const float* Wq   = (const float*)d_in[6];
    const float* bq   = (const float*)d_in[7];
    const float* Wv   = (const float*)d_in[8];
    const float* bv   = (const float*)d_in[9];
    const float* Wa   = (const float*)d_in[10];
    const float* ba   = (const float*)d_in[11];
    const float* pri  = (const float*)d_in[12];
    const float* Aatt = (const float*)d_in[13];
    const float* Amsg = (const float*)d_in[14];
    const float* skip = (const float*)d_in[15];
    const float* gam  = (const float*)d_in[16];
    const float* bet  = (const float*)d_in[17];

    char* ws = (char*)d_ws;
    float* Wkf = (float*)(ws + 0);
    float* Wvf = (float*)(ws + 524288);
    float* bkf = (float*)(ws + 1048576);
    float* bvf = (float*)(ws + 1052672);
    float* den = (float*)(ws + 1056768);
    float* num = (float*)(ws + 2105344);
    int*   cnt = (int*)  (ws + 18882560);
    int*   eperm = (int*)(ws + 19013632);
    int*   nperm = (int*)(ws + 20062208);
    int*   ectr  = (int*)(ws + 20193280);
    int*   nctr  = (int*)(ws + 20193536);

    const int* src = edge_idx;
    const int* dst = edge_idx + NE;

    // zero den+num+cnt (contiguous) and counters
    zero_f<<<2048, 256, 0, stream>>>(den, NN * NH + NN * CD + NN);
    zero_i<<<1, 128, 0, stream>>>(ectr, 128);
    fuse_weights<<<(2 * NR * CD * CD + 2 * NR * CD + 255) / 256, 256, 0, stream>>>(
        Wk, bk, Wv, bv, Aatt, Amsg, Wkf, bkf, Wvf, bvf);
    hist_kernel<<<(NE + 255) / 256, 256, 0, stream>>>(edge_attr, NE, ectr);
    hist_kernel<<<(NN + 255) / 256, 256, 0, stream>>>(type_id, NN, nctr);
    scan_buckets<<<1, 64, 0, stream>>>(ectr, nctr);
    scatter_kernel<<<(NE + 255) / 256, 256, 0, stream>>>(edge_attr, NE, ectr, eperm);
    scatter_kernel<<<(NN + 255) / 256, 256, 0, stream>>>(type_id, NN, nctr, nperm);
    edge_kernel<<<NE / 64 + NR, 256, 0, stream>>>(x, src, dst, Wq, bq, Wkf, bkf, Wvf, bvf,
                                                  pri, ectr, eperm, den, num, cnt);
    node_kernel<<<NN / 64 + NT, 256, 0, stream>>>(x, Wa, ba, skip, gam, bet, nctr, nperm,
                                                  den, num, cnt, (float*)d_out);
}

// Round 2
// 433.987 us; speedup vs baseline: 3.3882x; 3.3882x over previous
//
#include <hip/hip_runtime.h>
#include <math.h>

#define NN 32768
#define NE 262144
#define CD 128
#define NH 8
#define NT 8
#define NR 8

typedef unsigned short u16;
typedef __attribute__((ext_vector_type(8))) short bhalf8;
typedef __attribute__((ext_vector_type(4))) short short4v;
typedef __attribute__((ext_vector_type(4))) float f32x4;

// ---------------- workspace layout (bytes) ----------------
// WqT  @ 0         262144   (bf16 [T][n][k])
// WkT  @ 262144    262144   (fused rel_att)
// WvT  @ 524288    262144   (fused rel_msg)
// WaT  @ 786432    262144
// bkf  @ 1048576   4096     (fp32 fused bias)
// bvf  @ 1052672   4096
// den  @ 1056768   NN*NH*4   = 1048576
// num  @ 2105344   NN*CD*4   = 16777216
// cnt  @ 18882560  NN*4      = 131072
// eperm@ 19013632  NE*4      = 1048576
// nperm@ 20062208  NN*4      = 131072
// ectr @ 20193280  64 ints
// nctr @ 20193536  64 ints

__device__ __forceinline__ u16 f2b(float f) {
    union { float f; unsigned u; } v; v.f = f;
    unsigned r = v.u + 0x7FFF + ((v.u >> 16) & 1);
    return (u16)(r >> 16);
}

__global__ void zero_f(float* __restrict__ p, int n) {
    int i = blockIdx.x * blockDim.x + threadIdx.x;
    int stride = gridDim.x * blockDim.x;
    for (; i < n; i += stride) p[i] = 0.f;
}

__global__ void zero_i(int* __restrict__ p, int n) {
    int i = blockIdx.x * blockDim.x + threadIdx.x;
    if (i < n) p[i] = 0;
}

// build transposed bf16 weights: WqT/WaT plain transpose, WkT/WvT fused with
// relation_att/relation_msg; plus fp32 fused biases bkf/bvf
__global__ void prep_weights(const float* __restrict__ Wk, const float* __restrict__ bk,
                             const float* __restrict__ Wq,
                             const float* __restrict__ Wv, const float* __restrict__ bv,
                             const float* __restrict__ Wa,
                             const float* __restrict__ Aatt, const float* __restrict__ Amsg,
                             u16* __restrict__ WqT, u16* __restrict__ WkT,
                             u16* __restrict__ WvT, u16* __restrict__ WaT,
                             float* __restrict__ bkf, float* __restrict__ bvf) {
    const int WCNT = NT * CD * CD;  // 131072 per matrix
    int idx = blockIdx.x * 256 + threadIdx.x;
    if (idx < 4 * WCNT) {
        int mat = idx >> 17;
        int o = idx & (WCNT - 1);
        int t = o >> 14;
        int n = (o >> 7) & 127;
        int k = o & 127;
        if (mat == 0) {
            WqT[o] = f2b(Wq[(t * CD + k) * CD + n]);
        } else if (mat == 3) {
            WaT[o] = f2b(Wa[(t * CD + k) * CD + n]);
        } else {
            int h = n >> 4, j = n & 15;
            const float* W = (mat == 1) ? Wk : Wv;
            const float* A = (mat == 1) ? Aatt : Amsg;
            const float* wrow = W + (t * CD + k) * CD + h * 16;
            const float* acol = A + ((t * NH + h) * 16) * 16 + j;
            float s = 0.f;
#pragma unroll
            for (int d = 0; d < 16; ++d) s += wrow[d] * acol[d * 16];
            ((mat == 1) ? WkT : WvT)[o] = f2b(s);
        }
    } else {
        int o2 = idx - 4 * WCNT;
        if (o2 < 2 * NT * CD) {
            int which = (o2 >= NT * CD) ? 1 : 0;
            int o = o2 - which * NT * CD;
            const float* B = which ? bv : bk;
            const float* A = which ? Amsg : Aatt;
            int t = o >> 7; int c = o & 127; int h = c >> 4; int j = c & 15;
            const float* brow = B + t * CD + h * 16;
            const float* acol = A + ((t * NH + h) * 16) * 16 + j;
            float s = 0.f;
#pragma unroll
            for (int d = 0; d < 16; ++d) s += brow[d] * acol[d * 16];
            (which ? bvf : bkf)[o] = s;
        }
    }
}

__global__ void hist_kernel(const int* __restrict__ lab, int n, int* __restrict__ ctr) {
    __shared__ int lh[8];
    if (threadIdx.x < 8) lh[threadIdx.x] = 0;
    __syncthreads();
    int i = blockIdx.x * 256 + threadIdx.x;
    if (i < n) atomicAdd(&lh[lab[i]], 1);
    __syncthreads();
    if (threadIdx.x < 8 && lh[threadIdx.x]) atomicAdd(&ctr[threadIdx.x], lh[threadIdx.x]);
}

__global__ void scan_buckets(int* ectr, int* nctr) {
    int* c = nullptr;
    if (threadIdx.x == 0) c = ectr;
    else if (threadIdx.x == 1) c = nctr;
    if (c) {
        int acc = 0, ptb = 0;
        c[8] = 0; c[17] = 0;
        for (int u = 0; u < 8; ++u) {
            acc += c[u];  c[9 + u] = acc;
            ptb += (c[u] + 63) >> 6;  c[18 + u] = ptb;
            c[26 + u] = 0;
        }
    }
}

__global__ void scatter_kernel(const int* __restrict__ lab, int n,
                               int* __restrict__ ctr, int* __restrict__ perm) {
    __shared__ int lh[8];
    __shared__ int lbase[8];
    if (threadIdx.x < 8) lh[threadIdx.x] = 0;
    __syncthreads();
    int i = blockIdx.x * 256 + threadIdx.x;
    int t = 0, lpos = 0;
    bool v = (i < n);
    if (v) { t = lab[i]; lpos = atomicAdd(&lh[t], 1); }
    __syncthreads();
    if (threadIdx.x < 8)
        lbase[threadIdx.x] = lh[threadIdx.x] ? atomicAdd(&ctr[26 + threadIdx.x], lh[threadIdx.x]) : 0;
    __syncthreads();
    if (v) perm[ctr[8 + t] + lbase[t] + lpos] = i;
}

// stage one 128x128 bf16 weight tile (row-major [n][k]) into LDS, stride 136
__device__ __forceinline__ void stage_w(const u16* __restrict__ g, u16* __restrict__ s, int tid) {
#pragma unroll
    for (int it = 0; it < 8; ++it) {
        int c = tid + it * 256;        // 2048 chunks of 8 u16
        int row = c >> 4, off = (c & 15) * 8;
        *(bhalf8*)&s[row * 136 + off] = *(const bhalf8*)&g[row * 128 + off];
    }
}

// 64x128x128 bf16 MFMA GEMM, wave partition: 2 row-tiles (rh) x 4 col-tiles (ch)
__device__ __forceinline__ void gemm64(const u16* __restrict__ sA, const u16* __restrict__ sw,
                                       int rh, int ch, int lx, int quad,
                                       const float* __restrict__ biasRow, f32x4 acc[2][4]) {
#pragma unroll
    for (int nt = 0; nt < 4; ++nt) {
        float bv = biasRow[ch * 64 + nt * 16 + lx];
        acc[0][nt] = f32x4{bv, bv, bv, bv};
        acc[1][nt] = f32x4{bv, bv, bv, bv};
    }
    const int m0 = rh * 32 + lx;
#pragma unroll
    for (int kk = 0; kk < 4; ++kk) {
        int ko = kk * 32 + quad * 8;
        bhalf8 a0 = *(const bhalf8*)&sA[m0 * 136 + ko];
        bhalf8 a1 = *(const bhalf8*)&sA[(m0 + 16) * 136 + ko];
#pragma unroll
        for (int nt = 0; nt < 4; ++nt) {
            bhalf8 bb = *(const bhalf8*)&sw[(ch * 64 + nt * 16 + lx) * 136 + ko];
            acc[0][nt] = __builtin_amdgcn_mfma_f32_16x16x32_bf16(a0, bb, acc[0][nt], 0, 0, 0);
            acc[1][nt] = __builtin_amdgcn_mfma_f32_16x16x32_bf16(a1, bb, acc[1][nt], 0, 0, 0);
        }
    }
}

__launch_bounds__(256, 2)
__global__ void edge_kernel(const float* __restrict__ x,
                            const int* __restrict__ src, const int* __restrict__ dst,
                            const u16* __restrict__ WqT, const float* __restrict__ bq,
                            const u16* __restrict__ WkT, const float* __restrict__ bkf,
                            const u16* __restrict__ WvT, const float* __restrict__ bvf,
                            const float* __restrict__ pri,
                            const int* __restrict__ ectr, const int* __restrict__ eperm,
                            float* __restrict__ den, float* __restrict__ num,
                            int* __restrict__ cnt) {
    __shared__ u16 sFS[64 * 136];
    __shared__ u16 sFD[64 * 136];
    __shared__ u16 sW[128 * 136];
    __shared__ int sSrc[64], sDst[64], sVal[64];

    const int tid = threadIdx.x;
    const int lane = tid & 63;
    const int w = tid >> 6;
    const int lx = lane & 15;
    const int quad = lane >> 4;
    const int ch = w & 1;       // column half (heads ch*4 .. ch*4+3)
    const int rh = w >> 1;      // row half (edges rh*32 .. rh*32+31)
    const int b = blockIdx.x;

    int t = -1, lt = 0;
#pragma unroll
    for (int u = 0; u < NR; ++u) {
        int p0 = ectr[17 + u], p1 = ectr[18 + u];
        if (b >= p0 && b < p1) { t = u; lt = b - p0; }
    }
    if (t < 0) return;
    const int base = ectr[8 + t];
    const int sz = ectr[9 + t] - base;
    const int start = lt * 64;

    if (tid < 64) {
        int idx = start + tid;
        int e = (idx < sz) ? eperm[base + idx] : -1;
        sVal[tid] = (e >= 0) ? 1 : 0;
        sSrc[tid] = (e >= 0) ? src[e] : 0;
        sDst[tid] = (e >= 0) ? dst[e] : 0;
    }
    __syncthreads();

    // gather fs/fd rows -> bf16 LDS; stage WqT
#pragma unroll
    for (int it = 0; it < 8; ++it) {
        int c = tid + it * 256;
        int row = c >> 5, c4 = c & 31;
        float4 v = *((const float4*)(x + (long)sSrc[row] * CD) + c4);
        short4v pk; pk.x = (short)f2b(v.x); pk.y = (short)f2b(v.y);
        pk.z = (short)f2b(v.z); pk.w = (short)f2b(v.w);
        *(short4v*)&sFS[row * 136 + c4 * 4] = pk;
        float4 u2 = *((const float4*)(x + (long)sDst[row] * CD) + c4);
        short4v pk2; pk2.x = (short)f2b(u2.x); pk2.y = (short)f2b(u2.y);
        pk2.z = (short)f2b(u2.z); pk2.w = (short)f2b(u2.w);
        *(short4v*)&sFD[row * 136 + c4 * 4] = pk2;
    }
    stage_w(WqT + t * CD * CD, sW, tid);
    __syncthreads();

    f32x4 qa[2][4], ka[2][4];
    gemm64(sFD, sW, rh, ch, lx, quad, bq + t * CD, qa);
    __syncthreads();
    stage_w(WkT + t * CD * CD, sW, tid);
    __syncthreads();
    gemm64(sFS, sW, rh, ch, lx, quad, bkf + t * CD, ka);

    // attention: att[e][h] via elementwise q*kt + 16-lane reduce (head = ch*4+nt)
    float ex[2][4][4];
#pragma unroll
    for (int nt = 0; nt < 4; ++nt) {
        const float ph = pri[t * NH + ch * 4 + nt] * 0.25f;
#pragma unroll
        for (int mt = 0; mt < 2; ++mt) {
#pragma unroll
            for (int reg = 0; reg < 4; ++reg) {
                float p = qa[mt][nt][reg] * ka[mt][nt][reg];
                p += __shfl_xor(p, 1);
                p += __shfl_xor(p, 2);
                p += __shfl_xor(p, 4);
                p += __shfl_xor(p, 8);
                float e_ = expf(p * ph);
                ex[mt][nt][reg] = e_;
                int erow = rh * 32 + mt * 16 + quad * 4 + reg;
                if (lx == 0 && sVal[erow])
                    atomicAdd(&den[sDst[erow] * NH + ch * 4 + nt], e_);
            }
        }
    }
    if (tid < 64 && sVal[tid]) atomicAdd(&cnt[sDst[tid]], 1);
    __syncthreads();
    stage_w(WvT + t * CD * CD, sW, tid);
    __syncthreads();

    f32x4 va[2][4];
    gemm64(sFS, sW, rh, ch, lx, quad, bvf + t * CD, va);
#pragma unroll
    for (int mt = 0; mt < 2; ++mt)
#pragma unroll
        for (int reg = 0; reg < 4; ++reg) {
            int erow = rh * 32 + mt * 16 + quad * 4 + reg;
            if (!sVal[erow]) continue;
            float* np = num + (long)sDst[erow] * CD + ch * 64;
#pragma unroll
            for (int nt = 0; nt < 4; ++nt)
                atomicAdd(&np[nt * 16 + lx], ex[mt][nt][reg] * va[mt][nt][reg]);
        }
}

__launch_bounds__(256, 2)
__global__ void node_kernel(const float* __restrict__ x,
                            const u16* __restrict__ WaT, const float* __restrict__ ba,
                            const float* __restrict__ skip, const float* __restrict__ gamma,
                            const float* __restrict__ beta,
                            const int* __restrict__ nctr, const int* __restrict__ nperm,
                            const float* __restrict__ den, const float* __restrict__ num,
                            const int* __restrict__ cnt,
                            float* __restrict__ out) {
    __shared__ u16 sX0[64 * 136];
    __shared__ u16 sW[128 * 136];
    __shared__ int sNode[64], sVal[64];

    const int tid = threadIdx.x;
    const int lane = tid & 63;
    const int w = tid >> 6;
    const int lx = lane & 15;
    const int quad = lane >> 4;
    const int b = blockIdx.x;

    int t = -1, lt = 0;
#pragma unroll
    for (int u = 0; u < NT; ++u) {
        int p0 = nctr[17 + u], p1 = nctr[18 + u];
        if (b >= p0 && b < p1) { t = u; lt = b - p0; }
    }
    if (t < 0) return;
    const int base = nctr[8 + t];
    const int sz = nctr[9 + t] - base;
    const int start = lt * 64;

    if (tid < 64) {
        int idx = start + tid;
        int n = (idx < sz) ? nperm[base + idx] : -1;
        sVal[tid] = (n >= 0) ? 1 : 0;
        sNode[tid] = (n >= 0) ? n : 0;
    }
    __syncthreads();

    // x0 = num / (den * cnt) -> bf16 LDS; stage WaT
#pragma unroll
    for (int it = 0; it < 8; ++it) {
        int c = tid + it * 256;
        int row = c >> 5, c4 = c & 31;
        int n = sNode[row];
        int ct = cnt[n];
        float4 v = {0.f, 0.f, 0.f, 0.f};
        if (ct > 0) {
            v = *((const float4*)(num + (long)n * CD) + c4);
            float r = 1.f / (den[n * NH + (c4 >> 2)] * (float)ct);
            v.x *= r; v.y *= r; v.z *= r; v.w *= r;
        }
        short4v pk; pk.x = (short)f2b(v.x); pk.y = (short)f2b(v.y);
        pk.z = (short)f2b(v.z); pk.w = (short)f2b(v.w);
        *(short4v*)&sX0[row * 136 + c4 * 4] = pk;
    }
    stage_w(WaT + t * CD * CD, sW, tid);
    __syncthreads();

    // wave w: rows 16w..16w+15, all 8 col-tiles
    f32x4 acc[8];
#pragma unroll
    for (int nt = 0; nt < 8; ++nt) {
        float bv = ba[t * CD + nt * 16 + lx];
        acc[nt] = f32x4{bv, bv, bv, bv};
    }
    const int m0 = w * 16 + lx;
#pragma unroll
    for (int kk = 0; kk < 4; ++kk) {
        int ko = kk * 32 + quad * 8;
        bhalf8 a = *(const bhalf8*)&sX0[m0 * 136 + ko];
#pragma unroll
        for (int nt = 0; nt < 8; ++nt) {
            bhalf8 bb = *(const bhalf8*)&sW[(nt * 16 + lx) * 136 + ko];
            acc[nt] = __builtin_amdgcn_mfma_f32_16x16x32_bf16(a, bb, acc[nt], 0, 0, 0);
        }
    }

    const float alpha = 1.f / (1.f + expf(-skip[t]));
    const float oma = 1.f - alpha;
    float g[8], be[8];
#pragma unroll
    for (int nt = 0; nt < 8; ++nt) {
        g[nt] = gamma[t * CD + nt * 16 + lx];
        be[nt] = beta[t * CD + nt * 16 + lx];
    }
#pragma unroll
    for (int reg = 0; reg < 4; ++reg) {
        int erow = w * 16 + quad * 4 + reg;
        int n = sNode[erow];
        const float* xr = x + (long)n * CD;
        float o[8];
        float s1 = 0.f, s2 = 0.f;
#pragma unroll
        for (int nt = 0; nt < 8; ++nt) {
            float xv = xr[nt * 16 + lx];
            float ov = acc[nt][reg] * alpha + xv * oma;
            o[nt] = ov;
            s1 += ov;
            s2 += ov * ov;
        }
#pragma unroll
        for (int m = 1; m < 16; m <<= 1) {
            s1 += __shfl_xor(s1, m);
            s2 += __shfl_xor(s2, m);
        }
        float mu = s1 * (1.f / 128.f);
        float var = s2 * (1.f / 128.f) - mu * mu;
        float rs = rsqrtf(var + 1e-5f);
        if (sVal[erow]) {
            float* op = out + (long)n * CD;
#pragma unroll
            for (int nt = 0; nt < 8; ++nt)
                op[nt * 16 + lx] = (o[nt] - mu) * rs * g[nt] + be[nt];
        }
    }
}

extern "C" void kernel_launch(void* const* d_in, const int* in_sizes, int n_in,
                              void* d_out, int out_size, void* d_ws, size_t ws_size,
                              hipStream_t stream) {
    const float* x        = (const float*)d_in[0];
    const int*   type_id  = (const int*)d_in[1];
    const int*   edge_idx = (const int*)d_in[2];
    const int*   edge_attr= (const int*)d_in[3];
    const float* Wk   = (const float*)d_in[4];
    const float* bk   = (const float*)d_in[5];
    const float* Wq   = (const float*)d_in[6];
    const float* bq   = (const float*)d_in[7];
    const float* Wv   = (const float*)d_in[8];
    const float* bv   = (const float*)d_in[9];
    const float* Wa   = (const float*)d_in[10];
    const float* ba   = (const float*)d_in[11];
    const float* pri  = (const float*)d_in[12];
    const float* Aatt = (const float*)d_in[13];
    const float* Amsg = (const float*)d_in[14];
    const float* skip = (const float*)d_in[15];
    const float* gam  = (const float*)d_in[16];
    const float* bet  = (const float*)d_in[17];

    char* ws = (char*)d_ws;
    u16*   WqT = (u16*)(ws + 0);
    u16*   WkT = (u16*)(ws + 262144);
    u16*   WvT = (u16*)(ws + 524288);
    u16*   WaT = (u16*)(ws + 786432);
    float* bkf = (float*)(ws + 1048576);
    float* bvf = (float*)(ws + 1052672);
    float* den = (float*)(ws + 1056768);
    float* num = (float*)(ws + 2105344);
    int*   cnt = (int*)  (ws + 18882560);
    int*   eperm = (int*)(ws + 19013632);
    int*   nperm = (int*)(ws + 20062208);
    int*   ectr  = (int*)(ws + 20193280);
    int*   nctr  = (int*)(ws + 20193536);

    const int* src = edge_idx;
    const int* dst = edge_idx + NE;

    zero_f<<<2048, 256, 0, stream>>>(den, NN * NH + NN * CD + NN);
    zero_i<<<1, 128, 0, stream>>>(ectr, 128);
    prep_weights<<<(4 * NT * CD * CD + 2 * NT * CD + 255) / 256, 256, 0, stream>>>(
        Wk, bk, Wq, Wv, bv, Wa, Aatt, Amsg, WqT, WkT, WvT, WaT, bkf, bvf);
    hist_kernel<<<(NE + 255) / 256, 256, 0, stream>>>(edge_attr, NE, ectr);
    hist_kernel<<<(NN + 255) / 256, 256, 0, stream>>>(type_id, NN, nctr);
    scan_buckets<<<1, 64, 0, stream>>>(ectr, nctr);
    scatter_kernel<<<(NE + 255) / 256, 256, 0, stream>>>(edge_attr, NE, ectr, eperm);
    scatter_kernel<<<(NN + 255) / 256, 256, 0, stream>>>(type_id, NN, nctr, nperm);
    edge_kernel<<<NE / 64 + NR, 256, 0, stream>>>(x, src, dst, WqT, bq, WkT, bkf, WvT, bvf,
                                                  pri, ectr, eperm, den, num, cnt);
    node_kernel<<<NN / 64 + NT, 256, 0, stream>>>(x, WaT, ba, skip, gam, bet, nctr, nperm,
                                                  den, num, cnt, (float*)d_out);
}

// Round 3
// 344.860 us; speedup vs baseline: 4.2639x; 1.2584x over previous
//
#include <hip/hip_runtime.h>
#include <math.h>

#define NN 32768
#define NE 262144
#define CD 128
#define NH 8
#define NT 8
#define NR 8

typedef unsigned short u16;
typedef __attribute__((ext_vector_type(8))) short bhalf8;
typedef __attribute__((ext_vector_type(4))) short short4v;
typedef __attribute__((ext_vector_type(4))) float f32x4;

// ---------------- workspace layout (bytes) ----------------
// WqT  @ 0         262144   bf16 [T][n][k], 16B-chunk XOR-swizzled
// WkT  @ 262144    262144   (fused rel_att)
// WvT  @ 524288    262144   (fused rel_msg)
// WaT  @ 786432    262144
// bkf  @ 1048576   4096     fp32 fused bias
// bvf  @ 1052672   4096
// exs  @ 1056768   (NE+64)*8*4  = 8390656
// vts  @ 9447424   (NE+64)*128*2 = 67125248
// deg  @ 76572672  NN*4
// dcur @ 76703744  NN*4   (adjacent to deg for combined zeroing)
// dbase@ 76834816  NN*4
// eperm@ 76965888  NE*4
// nperm@ 78014464  NN*4
// ectr @ 78145536  64 ints
// nctr @ 78145792  64 ints

__device__ __forceinline__ u16 f2b(float f) {
    union { float f; unsigned u; } v; v.f = f;
    unsigned r = v.u + 0x7FFF + ((v.u >> 16) & 1);
    return (u16)(r >> 16);
}
__device__ __forceinline__ float b2f(unsigned h) {
    union { unsigned u; float f; } v; v.u = h << 16;
    return v.f;
}

__global__ void zero_i(int* __restrict__ p, int n) {
    int i = blockIdx.x * blockDim.x + threadIdx.x;
    if (i < n) p[i] = 0;
}

// build transposed bf16 weights (swizzled): WqT/WaT plain, WkT/WvT fused with
// relation_att/relation_msg; plus fp32 fused biases bkf/bvf
__global__ void prep_weights(const float* __restrict__ Wk, const float* __restrict__ bk,
                             const float* __restrict__ Wq,
                             const float* __restrict__ Wv, const float* __restrict__ bv,
                             const float* __restrict__ Wa,
                             const float* __restrict__ Aatt, const float* __restrict__ Amsg,
                             u16* __restrict__ WqT, u16* __restrict__ WkT,
                             u16* __restrict__ WvT, u16* __restrict__ WaT,
                             float* __restrict__ bkf, float* __restrict__ bvf) {
    const int WCNT = NT * CD * CD;  // 131072 per matrix
    int idx = blockIdx.x * 256 + threadIdx.x;
    if (idx < 4 * WCNT) {
        int mat = idx >> 17;
        int o = idx & (WCNT - 1);
        int t = o >> 14;
        int n = (o >> 7) & 127;
        int k = o & 127;
        // swizzled output offset: 16B chunk c = k>>3 XOR (n&7)
        int oo = t * 16384 + n * 128 + (((k >> 3) ^ (n & 7)) << 3) + (k & 7);
        if (mat == 0) {
            WqT[oo] = f2b(Wq[(t * CD + k) * CD + n]);
        } else if (mat == 3) {
            WaT[oo] = f2b(Wa[(t * CD + k) * CD + n]);
        } else {
            int h = n >> 4, j = n & 15;
            const float* W = (mat == 1) ? Wk : Wv;
            const float* A = (mat == 1) ? Aatt : Amsg;
            const float* wrow = W + (t * CD + k) * CD + h * 16;
            const float* acol = A + ((t * NH + h) * 16) * 16 + j;
            float s = 0.f;
#pragma unroll
            for (int d = 0; d < 16; ++d) s += wrow[d] * acol[d * 16];
            ((mat == 1) ? WkT : WvT)[oo] = f2b(s);
        }
    } else {
        int o2 = idx - 4 * WCNT;
        if (o2 < 2 * NT * CD) {
            int which = (o2 >= NT * CD) ? 1 : 0;
            int o = o2 - which * NT * CD;
            const float* B = which ? bv : bk;
            const float* A = which ? Amsg : Aatt;
            int t = o >> 7; int c = o & 127; int h = c >> 4; int j = c & 15;
            const float* brow = B + t * CD + h * 16;
            const float* acol = A + ((t * NH + h) * 16) * 16 + j;
            float s = 0.f;
#pragma unroll
            for (int d = 0; d < 16; ++d) s += brow[d] * acol[d * 16];
            (which ? bvf : bkf)[o] = s;
        }
    }
}

__global__ void hist_kernel(const int* __restrict__ lab, int n, int* __restrict__ ctr) {
    __shared__ int lh[8];
    if (threadIdx.x < 8) lh[threadIdx.x] = 0;
    __syncthreads();
    int i = blockIdx.x * 256 + threadIdx.x;
    if (i < n) atomicAdd(&lh[lab[i]], 1);
    __syncthreads();
    if (threadIdx.x < 8 && lh[threadIdx.x]) atomicAdd(&ctr[threadIdx.x], lh[threadIdx.x]);
}

__global__ void deg_hist(const int* __restrict__ dst, int* __restrict__ deg) {
    int i = blockIdx.x * 256 + threadIdx.x;
    if (i < NE) atomicAdd(&deg[dst[i]], 1);
}

__global__ void scan_buckets(int* ectr, int* nctr) {
    int* c = nullptr;
    if (threadIdx.x == 0) c = ectr;
    else if (threadIdx.x == 1) c = nctr;
    if (c) {
        int acc = 0, ptb = 0;
        c[8] = 0; c[17] = 0;
        for (int u = 0; u < 8; ++u) {
            acc += c[u];  c[9 + u] = acc;
            ptb += (c[u] + 63) >> 6;  c[18 + u] = ptb;
            c[26 + u] = 0;
        }
    }
}

// exclusive prefix over NN=32768 degree bins; 1024 threads x 32 each
__launch_bounds__(1024)
__global__ void prefix_kernel(const int* __restrict__ deg, int* __restrict__ dbase) {
    __shared__ int part[1024];
    int t = threadIdx.x;
    int local[32];
    int s = 0;
#pragma unroll
    for (int i = 0; i < 32; ++i) { local[i] = s; s += deg[t * 32 + i]; }
    part[t] = s;
    __syncthreads();
    for (int off = 1; off < 1024; off <<= 1) {
        int v = (t >= off) ? part[t - off] : 0;
        __syncthreads();
        part[t] += v;
        __syncthreads();
    }
    int base = (t == 0) ? 0 : part[t - 1];
#pragma unroll
    for (int i = 0; i < 32; ++i) dbase[t * 32 + i] = base + local[i];
}

__global__ void scatter_kernel(const int* __restrict__ lab, int n,
                               int* __restrict__ ctr, int* __restrict__ perm) {
    __shared__ int lh[8];
    __shared__ int lbase[8];
    if (threadIdx.x < 8) lh[threadIdx.x] = 0;
    __syncthreads();
    int i = blockIdx.x * 256 + threadIdx.x;
    int t = 0, lpos = 0;
    bool v = (i < n);
    if (v) { t = lab[i]; lpos = atomicAdd(&lh[t], 1); }
    __syncthreads();
    if (threadIdx.x < 8)
        lbase[threadIdx.x] = lh[threadIdx.x] ? atomicAdd(&ctr[26 + threadIdx.x], lh[threadIdx.x]) : 0;
    __syncthreads();
    if (v) perm[ctr[8 + t] + lbase[t] + lpos] = i;
}

// async-stage one 128x128 bf16 weight tile (pre-swizzled global) into flat LDS
__device__ __forceinline__ void stage_w(const u16* __restrict__ g, u16* __restrict__ s, int tid) {
#pragma unroll
    for (int it = 0; it < 8; ++it) {
        int chunk = it * 256 + tid;                 // 16B chunk index
        int wbase = it * 256 + (tid & ~63);         // wave-uniform chunk base
        __builtin_amdgcn_global_load_lds(
            (const __attribute__((address_space(1))) void*)(g + chunk * 8),
            (__attribute__((address_space(3))) void*)(s + wbase * 8), 16, 0, 0);
    }
}

// B-fragment read from swizzled LDS tile
__device__ __forceinline__ bhalf8 read_b(const u16* __restrict__ sw, int nrow, int kk, int quad) {
    int c = kk * 4 + quad;
    return *(const bhalf8*)&sw[nrow * 128 + (((c) ^ (nrow & 7)) << 3)];
}

// 64x128x128 bf16 MFMA GEMM, wave partition: 2 row-tiles (rh) x 2 col-halves (ch)
__device__ __forceinline__ void gemm64(const u16* __restrict__ sA, const u16* __restrict__ sw,
                                       int rh, int ch, int lx, int quad,
                                       const float* __restrict__ biasRow, f32x4 acc[2][4]) {
#pragma unroll
    for (int nt = 0; nt < 4; ++nt) {
        float bv = biasRow[ch * 64 + nt * 16 + lx];
        acc[0][nt] = f32x4{bv, bv, bv, bv};
        acc[1][nt] = f32x4{bv, bv, bv, bv};
    }
    const int m0 = rh * 32 + lx;
#pragma unroll
    for (int kk = 0; kk < 4; ++kk) {
        int ko = kk * 32 + quad * 8;
        bhalf8 a0 = *(const bhalf8*)&sA[m0 * 136 + ko];
        bhalf8 a1 = *(const bhalf8*)&sA[(m0 + 16) * 136 + ko];
#pragma unroll
        for (int nt = 0; nt < 4; ++nt) {
            bhalf8 bb = read_b(sw, ch * 64 + nt * 16 + lx, kk, quad);
            acc[0][nt] = __builtin_amdgcn_mfma_f32_16x16x32_bf16(a0, bb, acc[0][nt], 0, 0, 0);
            acc[1][nt] = __builtin_amdgcn_mfma_f32_16x16x32_bf16(a1, bb, acc[1][nt], 0, 0, 0);
        }
    }
}

__launch_bounds__(256, 2)
__global__ void edge_kernel(const float* __restrict__ x,
                            const int* __restrict__ src, const int* __restrict__ dst,
                            const u16* __restrict__ WqT, const float* __restrict__ bq,
                            const u16* __restrict__ WkT, const float* __restrict__ bkf,
                            const u16* __restrict__ WvT, const float* __restrict__ bvf,
                            const float* __restrict__ pri,
                            const int* __restrict__ ectr, const int* __restrict__ eperm,
                            const int* __restrict__ dbase, int* __restrict__ dcur,
                            float* __restrict__ exs, u16* __restrict__ vts) {
    __shared__ u16 sFS[64 * 136];
    __shared__ u16 sFD[64 * 136];   // holds fd; later reused as vt staging
    __shared__ u16 sW[128 * 128];
    __shared__ int sSrc[64], sDst[64], sVal[64], sPos[64];

    const int tid = threadIdx.x;
    const int lane = tid & 63;
    const int w = tid >> 6;
    const int lx = lane & 15;
    const int quad = lane >> 4;
    const int ch = w & 1;
    const int rh = w >> 1;
    const int b = blockIdx.x;

    int t = -1, lt = 0;
#pragma unroll
    for (int u = 0; u < NR; ++u) {
        int p0 = ectr[17 + u], p1 = ectr[18 + u];
        if (b >= p0 && b < p1) { t = u; lt = b - p0; }
    }
    if (t < 0) return;
    const int base = ectr[8 + t];
    const int sz = ectr[9 + t] - base;
    const int start = lt * 64;

    if (tid < 64) {
        int idx = start + tid;
        int e = (idx < sz) ? eperm[base + idx] : -1;
        int valid = (e >= 0) ? 1 : 0;
        sVal[tid] = valid;
        int d = valid ? dst[e] : 0;
        sSrc[tid] = valid ? src[e] : 0;
        sDst[tid] = d;
        sPos[tid] = valid ? (dbase[d] + atomicAdd(&dcur[d], 1)) : NE;
    }
    stage_w(WqT + t * CD * CD, sW, tid);
    __syncthreads();

    // gather fs/fd rows -> bf16 LDS
#pragma unroll
    for (int it = 0; it < 8; ++it) {
        int c = tid + it * 256;
        int row = c >> 5, c4 = c & 31;
        float4 v = *((const float4*)(x + (long)sSrc[row] * CD) + c4);
        short4v pk; pk.x = (short)f2b(v.x); pk.y = (short)f2b(v.y);
        pk.z = (short)f2b(v.z); pk.w = (short)f2b(v.w);
        *(short4v*)&sFS[row * 136 + c4 * 4] = pk;
        float4 u2 = *((const float4*)(x + (long)sDst[row] * CD) + c4);
        short4v pk2; pk2.x = (short)f2b(u2.x); pk2.y = (short)f2b(u2.y);
        pk2.z = (short)f2b(u2.z); pk2.w = (short)f2b(u2.w);
        *(short4v*)&sFD[row * 136 + c4 * 4] = pk2;
    }
    __syncthreads();

    f32x4 qa[2][4], ka[2][4];
    gemm64(sFD, sW, rh, ch, lx, quad, bq + t * CD, qa);
    __syncthreads();
    stage_w(WkT + t * CD * CD, sW, tid);
    __syncthreads();
    gemm64(sFS, sW, rh, ch, lx, quad, bkf + t * CD, ka);

    // attention: ex = exp(q.kt * pri / 4); write exs[p][ch*4..ch*4+3]
    float ex[2][4][4];
#pragma unroll
    for (int nt = 0; nt < 4; ++nt) {
        const float ph = pri[t * NH + ch * 4 + nt] * 0.25f;
#pragma unroll
        for (int mt = 0; mt < 2; ++mt) {
#pragma unroll
            for (int reg = 0; reg < 4; ++reg) {
                float p = qa[mt][nt][reg] * ka[mt][nt][reg];
                p += __shfl_xor(p, 1);
                p += __shfl_xor(p, 2);
                p += __shfl_xor(p, 4);
                p += __shfl_xor(p, 8);
                ex[mt][nt][reg] = expf(p * ph);
            }
        }
    }
    if (lx == 0) {
#pragma unroll
        for (int mt = 0; mt < 2; ++mt)
#pragma unroll
            for (int reg = 0; reg < 4; ++reg) {
                int erow = rh * 32 + mt * 16 + quad * 4 + reg;
                float4 e4 = {ex[mt][0][reg], ex[mt][1][reg], ex[mt][2][reg], ex[mt][3][reg]};
                *(float4*)(exs + (long)sPos[erow] * 8 + ch * 4) = e4;
            }
    }
    __syncthreads();
    stage_w(WvT + t * CD * CD, sW, tid);
    __syncthreads();

    f32x4 va[2][4];
    gemm64(sFS, sW, rh, ch, lx, quad, bvf + t * CD, va);
    // park vt (bf16) into sFD, then coalesced writeout to vts[p][*]
#pragma unroll
    for (int mt = 0; mt < 2; ++mt)
#pragma unroll
        for (int reg = 0; reg < 4; ++reg) {
            int erow = rh * 32 + mt * 16 + quad * 4 + reg;
#pragma unroll
            for (int nt = 0; nt < 4; ++nt)
                sFD[erow * 136 + ch * 64 + nt * 16 + lx] = f2b(va[mt][nt][reg]);
        }
    __syncthreads();
#pragma unroll
    for (int it = 0; it < 4; ++it) {
        int c = tid + it * 256;         // 1024 chunks: 64 rows x 16
        int row = c >> 4, off = (c & 15) * 8;
        *(bhalf8*)&vts[(long)sPos[row] * 128 + off] = *(const bhalf8*)&sFD[row * 136 + off];
    }
}

__launch_bounds__(256, 2)
__global__ void node_kernel(const float* __restrict__ x,
                            const u16* __restrict__ WaT, const float* __restrict__ ba,
                            const float* __restrict__ skip, const float* __restrict__ gamma,
                            const float* __restrict__ beta,
                            const int* __restrict__ nctr, const int* __restrict__ nperm,
                            const int* __restrict__ dbase, const int* __restrict__ deg,
                            const float* __restrict__ exs, const u16* __restrict__ vts,
                            float* __restrict__ out) {
    __shared__ u16 sX0[64 * 136];
    __shared__ u16 sW[128 * 128];
    __shared__ int sNode[64], sVal[64];

    const int tid = threadIdx.x;
    const int lane = tid & 63;
    const int w = tid >> 6;
    const int lx = lane & 15;
    const int quad = lane >> 4;
    const int b = blockIdx.x;

    int t = -1, lt = 0;
#pragma unroll
    for (int u = 0; u < NT; ++u) {
        int p0 = nctr[17 + u], p1 = nctr[18 + u];
        if (b >= p0 && b < p1) { t = u; lt = b - p0; }
    }
    if (t < 0) return;
    const int base = nctr[8 + t];
    const int sz = nctr[9 + t] - base;
    const int start = lt * 64;

    if (tid < 64) {
        int idx = start + tid;
        int n = (idx < sz) ? nperm[base + idx] : -1;
        sVal[tid] = (n >= 0) ? 1 : 0;
        sNode[tid] = (n >= 0) ? n : 0;
    }
    stage_w(WaT + t * CD * CD, sW, tid);
    __syncthreads();

    // x0[n] = sum_p ex[p][h]*vt[p][c] / (den[h]*deg): wave w builds rows 16w..16w+15
    {
        const int h = lane >> 3;   // head of cols 2*lane, 2*lane+1
        for (int r = 0; r < 16; ++r) {
            int row = w * 16 + r;
            int n = sNode[row];
            int s = dbase[n], d = deg[n];
            float a0 = 0.f, a1 = 0.f, sden = 0.f;
            const u16* vp = vts + (long)s * 128 + 2 * lane;
            const float* ep = exs + (long)s * 8 + h;
            for (int j = 0; j < d; ++j) {
                unsigned pk = *(const unsigned*)(vp + (long)j * 128);
                float e_ = ep[(long)j * 8];
                a0 += e_ * b2f(pk & 0xffffu);
                a1 += e_ * b2f(pk >> 16);
                sden += e_;
            }
            float inv = (d > 0) ? 1.f / (sden * (float)d) : 0.f;
            unsigned packed = (unsigned)f2b(a0 * inv) | ((unsigned)f2b(a1 * inv) << 16);
            *(unsigned*)&sX0[row * 136 + 2 * lane] = packed;
        }
    }
    __syncthreads();

    // wave w: rows 16w..16w+15, all 8 col-tiles
    f32x4 acc[8];
#pragma unroll
    for (int nt = 0; nt < 8; ++nt) {
        float bv = ba[t * CD + nt * 16 + lx];
        acc[nt] = f32x4{bv, bv, bv, bv};
    }
    const int m0 = w * 16 + lx;
#pragma unroll
    for (int kk = 0; kk < 4; ++kk) {
        int ko = kk * 32 + quad * 8;
        bhalf8 a = *(const bhalf8*)&sX0[m0 * 136 + ko];
#pragma unroll
        for (int nt = 0; nt < 8; ++nt) {
            bhalf8 bb = read_b(sW, nt * 16 + lx, kk, quad);
            acc[nt] = __builtin_amdgcn_mfma_f32_16x16x32_bf16(a, bb, acc[nt], 0, 0, 0);
        }
    }

    const float alpha = 1.f / (1.f + expf(-skip[t]));
    const float oma = 1.f - alpha;
    float g[8], be[8];
#pragma unroll
    for (int nt = 0; nt < 8; ++nt) {
        g[nt] = gamma[t * CD + nt * 16 + lx];
        be[nt] = beta[t * CD + nt * 16 + lx];
    }
#pragma unroll
    for (int reg = 0; reg < 4; ++reg) {
        int erow = w * 16 + quad * 4 + reg;
        int n = sNode[erow];
        const float* xr = x + (long)n * CD;
        float o[8];
        float s1 = 0.f, s2 = 0.f;
#pragma unroll
        for (int nt = 0; nt < 8; ++nt) {
            float xv = xr[nt * 16 + lx];
            float ov = acc[nt][reg] * alpha + xv * oma;
            o[nt] = ov;
            s1 += ov;
            s2 += ov * ov;
        }
#pragma unroll
        for (int m = 1; m < 16; m <<= 1) {
            s1 += __shfl_xor(s1, m);
            s2 += __shfl_xor(s2, m);
        }
        float mu = s1 * (1.f / 128.f);
        float var = s2 * (1.f / 128.f) - mu * mu;
        float rs = rsqrtf(var + 1e-5f);
        if (sVal[erow]) {
            float* op = out + (long)n * CD;
#pragma unroll
            for (int nt = 0; nt < 8; ++nt)
                op[nt * 16 + lx] = (o[nt] - mu) * rs * g[nt] + be[nt];
        }
    }
}

extern "C" void kernel_launch(void* const* d_in, const int* in_sizes, int n_in,
                              void* d_out, int out_size, void* d_ws, size_t ws_size,
                              hipStream_t stream) {
    const float* x        = (const float*)d_in[0];
    const int*   type_id  = (const int*)d_in[1];
    const int*   edge_idx = (const int*)d_in[2];
    const int*   edge_attr= (const int*)d_in[3];
    const float* Wk   = (const float*)d_in[4];
    const float* bk   = (const float*)d_in[5];
    const float* Wq   = (const float*)d_in[6];
    const float* bq   = (const float*)d_in[7];
    const float* Wv   = (const float*)d_in[8];
    const float* bv   = (const float*)d_in[9];
    const float* Wa   = (const float*)d_in[10];
    const float* ba   = (const float*)d_in[11];
    const float* pri  = (const float*)d_in[12];
    const float* Aatt = (const float*)d_in[13];
    const float* Amsg = (const float*)d_in[14];
    const float* skip = (const float*)d_in[15];
    const float* gam  = (const float*)d_in[16];
    const float* bet  = (const float*)d_in[17];

    char* ws = (char*)d_ws;
    u16*   WqT  = (u16*)(ws + 0);
    u16*   WkT  = (u16*)(ws + 262144);
    u16*   WvT  = (u16*)(ws + 524288);
    u16*   WaT  = (u16*)(ws + 786432);
    float* bkf  = (float*)(ws + 1048576);
    float* bvf  = (float*)(ws + 1052672);
    float* exs  = (float*)(ws + 1056768);
    u16*   vts  = (u16*)(ws + 9447424);
    int*   deg  = (int*)  (ws + 76572672);
    int*   dcur = (int*)  (ws + 76703744);
    int*   dbase= (int*)  (ws + 76834816);
    int*   eperm= (int*)  (ws + 76965888);
    int*   nperm= (int*)  (ws + 78014464);
    int*   ectr = (int*)  (ws + 78145536);
    int*   nctr = (int*)  (ws + 78145792);

    const int* src = edge_idx;
    const int* dst = edge_idx + NE;

    zero_i<<<(2 * NN + 255) / 256, 256, 0, stream>>>(deg, 2 * NN);  // deg + dcur
    zero_i<<<1, 128, 0, stream>>>(ectr, 128);
    prep_weights<<<(4 * NT * CD * CD + 2 * NT * CD + 255) / 256, 256, 0, stream>>>(
        Wk, bk, Wq, Wv, bv, Wa, Aatt, Amsg, WqT, WkT, WvT, WaT, bkf, bvf);
    hist_kernel<<<(NE + 255) / 256, 256, 0, stream>>>(edge_attr, NE, ectr);
    hist_kernel<<<(NN + 255) / 256, 256, 0, stream>>>(type_id, NN, nctr);
    deg_hist<<<(NE + 255) / 256, 256, 0, stream>>>(dst, deg);
    scan_buckets<<<1, 64, 0, stream>>>(ectr, nctr);
    prefix_kernel<<<1, 1024, 0, stream>>>(deg, dbase);
    scatter_kernel<<<(NE + 255) / 256, 256, 0, stream>>>(edge_attr, NE, ectr, eperm);
    scatter_kernel<<<(NN + 255) / 256, 256, 0, stream>>>(type_id, NN, nctr, nperm);
    edge_kernel<<<NE / 64 + NR, 256, 0, stream>>>(x, src, dst, WqT, bq, WkT, bkf, WvT, bvf,
                                                  pri, ectr, eperm, dbase, dcur, exs, vts);
    node_kernel<<<NN / 64 + NT, 256, 0, stream>>>(x, WaT, ba, skip, gam, bet, nctr, nperm,
                                                  dbase, deg, exs, vts, (float*)d_out);
}

// Round 4
// 293.620 us; speedup vs baseline: 5.0080x; 1.1745x over previous
//
#include <hip/hip_runtime.h>
#include <math.h>

#define NN 32768
#define NE 262144
#define CD 128
#define NH 8
#define NT 8
#define NR 8

typedef unsigned short u16;
typedef __attribute__((ext_vector_type(8))) short bhalf8;
typedef __attribute__((ext_vector_type(4))) short short4v;
typedef __attribute__((ext_vector_type(4))) float f32x4;

// ---------------- workspace layout (bytes) ----------------
// WqT  @ 0         262144   bf16, MFMA-fragment order [t][ct][kk][lane][8]
// WkT  @ 262144    262144   (fused rel_att)
// WvT  @ 524288    262144   (fused rel_msg)
// WaT  @ 786432    262144
// bkf  @ 1048576   4096     fp32 fused bias
// bvf  @ 1052672   4096
// exs  @ 1056768   (NE+64)*8*4  = 8390656
// vts  @ 9447424   (NE+64)*128*2 = 67125248
// deg  @ 76572672  NN*4
// dcur @ 76703744  NN*4   (adjacent to deg for combined zeroing)
// dbase@ 76834816  NN*4
// eperm@ 76965888  NE*4
// nperm@ 78014464  NN*4
// ectr @ 78145536  64 ints   (adjacent to nctr)
// nctr @ 78145792  64 ints

__device__ __forceinline__ u16 f2b(float f) {
    union { float f; unsigned u; } v; v.f = f;
    unsigned r = v.u + 0x7FFF + ((v.u >> 16) & 1);
    return (u16)(r >> 16);
}
__device__ __forceinline__ float b2f(unsigned h) {
    union { unsigned u; float f; } v; v.u = h << 16;
    return v.f;
}

__global__ void zero_all(int* __restrict__ degd, int* __restrict__ ctrs) {
    int i = blockIdx.x * 256 + threadIdx.x;
    if (i < 2 * NN) degd[i] = 0;
    else if (i < 2 * NN + 128) ctrs[i - 2 * NN] = 0;
}

// build bf16 weights in MFMA-fragment order: element (t, col n, row k) ->
// off = t*16384 + ((ct*4+kk)*64 + quad*16 + lx)*8 + d  with ct=n>>4, lx=n&15,
// kk=k>>5, quad=(k>>3)&3, d=k&7. WqT/WaT plain, WkT/WvT fused with relations.
__global__ void prep_weights(const float* __restrict__ Wk, const float* __restrict__ bk,
                             const float* __restrict__ Wq,
                             const float* __restrict__ Wv, const float* __restrict__ bv,
                             const float* __restrict__ Wa,
                             const float* __restrict__ Aatt, const float* __restrict__ Amsg,
                             u16* __restrict__ WqT, u16* __restrict__ WkT,
                             u16* __restrict__ WvT, u16* __restrict__ WaT,
                             float* __restrict__ bkf, float* __restrict__ bvf) {
    const int WCNT = NT * CD * CD;  // 131072 per matrix
    int idx = blockIdx.x * 256 + threadIdx.x;
    if (idx < 4 * WCNT) {
        int mat = idx >> 17;
        int o = idx & (WCNT - 1);
        int t = o >> 14;
        int n = (o >> 7) & 127;
        int k = o & 127;
        int ct = n >> 4, lx2 = n & 15, kk = k >> 5, qd = (k >> 3) & 3, dd = k & 7;
        int oo = t * 16384 + (((ct * 4 + kk) * 4 + qd) * 16 + lx2) * 8 + dd;
        if (mat == 0) {
            WqT[oo] = f2b(Wq[(t * CD + k) * CD + n]);
        } else if (mat == 3) {
            WaT[oo] = f2b(Wa[(t * CD + k) * CD + n]);
        } else {
            int h = n >> 4, j = n & 15;
            const float* W = (mat == 1) ? Wk : Wv;
            const float* A = (mat == 1) ? Aatt : Amsg;
            const float* wrow = W + (t * CD + k) * CD + h * 16;
            const float* acol = A + ((t * NH + h) * 16) * 16 + j;
            float s = 0.f;
#pragma unroll
            for (int d = 0; d < 16; ++d) s += wrow[d] * acol[d * 16];
            ((mat == 1) ? WkT : WvT)[oo] = f2b(s);
        }
    } else {
        int o2 = idx - 4 * WCNT;
        if (o2 < 2 * NT * CD) {
            int which = (o2 >= NT * CD) ? 1 : 0;
            int o = o2 - which * NT * CD;
            const float* B = which ? bv : bk;
            const float* A = which ? Amsg : Aatt;
            int t = o >> 7; int c = o & 127; int h = c >> 4; int j = c & 15;
            const float* brow = B + t * CD + h * 16;
            const float* acol = A + ((t * NH + h) * 16) * 16 + j;
            float s = 0.f;
#pragma unroll
            for (int d = 0; d < 16; ++d) s += brow[d] * acol[d * 16];
            (which ? bvf : bkf)[o] = s;
        }
    }
}

// all three histograms in one launch
__global__ void hists(const int* __restrict__ ea, const int* __restrict__ tidv,
                      const int* __restrict__ dstv,
                      int* __restrict__ ectr, int* __restrict__ nctr, int* __restrict__ deg) {
    __shared__ int lh[16];
    if (threadIdx.x < 16) lh[threadIdx.x] = 0;
    __syncthreads();
    int i = blockIdx.x * 256 + threadIdx.x;
    if (i < NE) { atomicAdd(&lh[ea[i]], 1); atomicAdd(&deg[dstv[i]], 1); }
    if (i < NN) atomicAdd(&lh[8 + tidv[i]], 1);
    __syncthreads();
    int v = (threadIdx.x < 16) ? lh[threadIdx.x] : 0;
    if (threadIdx.x < 8 && v) atomicAdd(&ectr[threadIdx.x], v);
    if (threadIdx.x >= 8 && threadIdx.x < 16 && v) atomicAdd(&nctr[threadIdx.x - 8], v);
}

// block 0: exclusive prefix over NN degree bins; block 1: bucket scans
__launch_bounds__(1024)
__global__ void scan_prefix(const int* __restrict__ deg, int* __restrict__ dbase,
                            int* __restrict__ ectr, int* __restrict__ nctr) {
    if (blockIdx.x == 1) {
        int* c = nullptr;
        if (threadIdx.x == 0) c = ectr;
        else if (threadIdx.x == 1) c = nctr;
        if (c) {
            int acc = 0, ptb = 0;
            c[8] = 0; c[17] = 0;
            for (int u = 0; u < 8; ++u) {
                acc += c[u];  c[9 + u] = acc;
                ptb += (c[u] + 63) >> 6;  c[18 + u] = ptb;
                c[26 + u] = 0;
            }
        }
        return;
    }
    __shared__ int part[1024];
    int t = threadIdx.x;
    int local[32];
    int s = 0;
#pragma unroll
    for (int i = 0; i < 32; ++i) { local[i] = s; s += deg[t * 32 + i]; }
    part[t] = s;
    __syncthreads();
    for (int off = 1; off < 1024; off <<= 1) {
        int v = (t >= off) ? part[t - off] : 0;
        __syncthreads();
        part[t] += v;
        __syncthreads();
    }
    int base = (t == 0) ? 0 : part[t - 1];
#pragma unroll
    for (int i = 0; i < 32; ++i) dbase[t * 32 + i] = base + local[i];
}

// both stable scatters in one launch
__global__ void scatters(const int* __restrict__ ea, const int* __restrict__ tidv,
                         int* __restrict__ ectr, int* __restrict__ nctr,
                         int* __restrict__ eperm, int* __restrict__ nperm) {
    __shared__ int lh[8];
    __shared__ int lbase[8];
    const int b = blockIdx.x;
    const int* lab; int* ctr; int* perm; int i; int n;
    if (b < NE / 256) { lab = ea; ctr = ectr; perm = eperm; i = b * 256 + threadIdx.x; n = NE; }
    else { lab = tidv; ctr = nctr; perm = nperm; i = (b - NE / 256) * 256 + threadIdx.x; n = NN; }
    if (threadIdx.x < 8) lh[threadIdx.x] = 0;
    __syncthreads();
    int t = 0, lpos = 0;
    bool v = (i < n);
    if (v) { t = lab[i]; lpos = atomicAdd(&lh[t], 1); }
    __syncthreads();
    if (threadIdx.x < 8)
        lbase[threadIdx.x] = lh[threadIdx.x] ? atomicAdd(&ctr[26 + threadIdx.x], lh[threadIdx.x]) : 0;
    __syncthreads();
    if (v) perm[ctr[8 + t] + lbase[t] + lpos] = i;
}

// 64x128x128 bf16 MFMA GEMM; B-fragments read directly from global (L2-hot),
// double-buffered over kk. gW points at the type's fragment-ordered matrix.
__device__ __forceinline__ void gemm64g(const u16* __restrict__ sA,
                                        const u16* __restrict__ gW,
                                        int rh, int ch, int lx, int quad, int lane,
                                        const float* __restrict__ biasRow,
                                        f32x4 acc[2][4]) {
#pragma unroll
    for (int nt = 0; nt < 4; ++nt) {
        float bv = biasRow[ch * 64 + nt * 16 + lx];
        acc[0][nt] = f32x4{bv, bv, bv, bv};
        acc[1][nt] = f32x4{bv, bv, bv, bv};
    }
    const int m0 = rh * 32 + lx;
    const u16* wbase = gW + (ch * 4) * 2048 + lane * 8;  // ct stride 2048 u16, kk stride 512 u16
    bhalf8 bb[2][4];
#pragma unroll
    for (int nt = 0; nt < 4; ++nt)
        bb[0][nt] = *(const bhalf8*)(wbase + nt * 2048);
#pragma unroll
    for (int kk = 0; kk < 4; ++kk) {
        if (kk < 3) {
#pragma unroll
            for (int nt = 0; nt < 4; ++nt)
                bb[(kk + 1) & 1][nt] = *(const bhalf8*)(wbase + nt * 2048 + (kk + 1) * 512);
        }
        const int ko = kk * 32 + quad * 8;
        bhalf8 a0 = *(const bhalf8*)&sA[m0 * 136 + ko];
        bhalf8 a1 = *(const bhalf8*)&sA[(m0 + 16) * 136 + ko];
#pragma unroll
        for (int nt = 0; nt < 4; ++nt) {
            acc[0][nt] = __builtin_amdgcn_mfma_f32_16x16x32_bf16(a0, bb[kk & 1][nt], acc[0][nt], 0, 0, 0);
            acc[1][nt] = __builtin_amdgcn_mfma_f32_16x16x32_bf16(a1, bb[kk & 1][nt], acc[1][nt], 0, 0, 0);
        }
    }
}

__launch_bounds__(256, 3)
__global__ void edge_kernel(const float* __restrict__ x,
                            const int* __restrict__ src, const int* __restrict__ dst,
                            const u16* __restrict__ WqT, const float* __restrict__ bq,
                            const u16* __restrict__ WkT, const float* __restrict__ bkf,
                            const u16* __restrict__ WvT, const float* __restrict__ bvf,
                            const float* __restrict__ pri,
                            const int* __restrict__ ectr, const int* __restrict__ eperm,
                            const int* __restrict__ dbase, int* __restrict__ dcur,
                            float* __restrict__ exs, u16* __restrict__ vts) {
    __shared__ u16 sFS[64 * 136];
    __shared__ u16 sFD[64 * 136];   // fd; later reused as vt staging
    __shared__ int sSrc[64], sDst[64], sPos[64];

    const int tid = threadIdx.x;
    const int lane = tid & 63;
    const int w = tid >> 6;
    const int lx = lane & 15;
    const int quad = lane >> 4;
    const int ch = w & 1;
    const int rh = w >> 1;
    const int b = blockIdx.x;

    int t = -1, lt = 0;
#pragma unroll
    for (int u = 0; u < NR; ++u) {
        int p0 = ectr[17 + u], p1 = ectr[18 + u];
        if (b >= p0 && b < p1) { t = u; lt = b - p0; }
    }
    if (t < 0) return;
    const int base = ectr[8 + t];
    const int sz = ectr[9 + t] - base;
    const int start = lt * 64;

    if (tid < 64) {
        int idx = start + tid;
        int e = (idx < sz) ? eperm[base + idx] : -1;
        int valid = (e >= 0) ? 1 : 0;
        int d = valid ? dst[e] : 0;
        sSrc[tid] = valid ? src[e] : 0;
        sDst[tid] = d;
        sPos[tid] = valid ? (dbase[d] + atomicAdd(&dcur[d], 1)) : NE;
    }
    __syncthreads();

    // gather fs/fd rows -> bf16 LDS
#pragma unroll
    for (int it = 0; it < 8; ++it) {
        int c = tid + it * 256;
        int row = c >> 5, c4 = c & 31;
        float4 v = *((const float4*)(x + (long)sSrc[row] * CD) + c4);
        short4v pk; pk.x = (short)f2b(v.x); pk.y = (short)f2b(v.y);
        pk.z = (short)f2b(v.z); pk.w = (short)f2b(v.w);
        *(short4v*)&sFS[row * 136 + c4 * 4] = pk;
        float4 u2 = *((const float4*)(x + (long)sDst[row] * CD) + c4);
        short4v pk2; pk2.x = (short)f2b(u2.x); pk2.y = (short)f2b(u2.y);
        pk2.z = (short)f2b(u2.z); pk2.w = (short)f2b(u2.w);
        *(short4v*)&sFD[row * 136 + c4 * 4] = pk2;
    }
    __syncthreads();

    f32x4 qa[2][4], ka[2][4];
    gemm64g(sFD, WqT + t * 16384, rh, ch, lx, quad, lane, bq + t * CD, qa);
    gemm64g(sFS, WkT + t * 16384, rh, ch, lx, quad, lane, bkf + t * CD, ka);

    // attention: ex = exp(q.kt * pri / 4); write exs[p][ch*4..ch*4+3]
    float ex[2][4][4];
#pragma unroll
    for (int nt = 0; nt < 4; ++nt) {
        const float ph = pri[t * NH + ch * 4 + nt] * 0.25f;
#pragma unroll
        for (int mt = 0; mt < 2; ++mt) {
#pragma unroll
            for (int reg = 0; reg < 4; ++reg) {
                float p = qa[mt][nt][reg] * ka[mt][nt][reg];
                p += __shfl_xor(p, 1);
                p += __shfl_xor(p, 2);
                p += __shfl_xor(p, 4);
                p += __shfl_xor(p, 8);
                ex[mt][nt][reg] = expf(p * ph);
            }
        }
    }
    if (lx == 0) {
#pragma unroll
        for (int mt = 0; mt < 2; ++mt)
#pragma unroll
            for (int reg = 0; reg < 4; ++reg) {
                int erow = rh * 32 + mt * 16 + quad * 4 + reg;
                float4 e4 = {ex[mt][0][reg], ex[mt][1][reg], ex[mt][2][reg], ex[mt][3][reg]};
                *(float4*)(exs + (long)sPos[erow] * 8 + ch * 4) = e4;
            }
    }

    f32x4 va[2][4];
    gemm64g(sFS, WvT + t * 16384, rh, ch, lx, quad, lane, bvf + t * CD, va);
    __syncthreads();
    // park vt (bf16) into sFD, then coalesced writeout to vts[p][*]
#pragma unroll
    for (int mt = 0; mt < 2; ++mt)
#pragma unroll
        for (int reg = 0; reg < 4; ++reg) {
            int erow = rh * 32 + mt * 16 + quad * 4 + reg;
#pragma unroll
            for (int nt = 0; nt < 4; ++nt)
                sFD[erow * 136 + ch * 64 + nt * 16 + lx] = f2b(va[mt][nt][reg]);
        }
    __syncthreads();
#pragma unroll
    for (int it = 0; it < 4; ++it) {
        int c = tid + it * 256;         // 1024 chunks: 64 rows x 16
        int row = c >> 4, off = (c & 15) * 8;
        *(bhalf8*)&vts[(long)sPos[row] * 128 + off] = *(const bhalf8*)&sFD[row * 136 + off];
    }
}

__launch_bounds__(256, 4)
__global__ void node_kernel(const float* __restrict__ x,
                            const u16* __restrict__ WaT, const float* __restrict__ ba,
                            const float* __restrict__ skip, const float* __restrict__ gamma,
                            const float* __restrict__ beta,
                            const int* __restrict__ nctr, const int* __restrict__ nperm,
                            const int* __restrict__ dbase, const int* __restrict__ deg,
                            const float* __restrict__ exs, const u16* __restrict__ vts,
                            float* __restrict__ out) {
    __shared__ u16 sX0[64 * 136];
    __shared__ int sNode[64], sVal[64];

    const int tid = threadIdx.x;
    const int lane = tid & 63;
    const int w = tid >> 6;
    const int lx = lane & 15;
    const int quad = lane >> 4;
    const int b = blockIdx.x;

    int t = -1, lt = 0;
#pragma unroll
    for (int u = 0; u < NT; ++u) {
        int p0 = nctr[17 + u], p1 = nctr[18 + u];
        if (b >= p0 && b < p1) { t = u; lt = b - p0; }
    }
    if (t < 0) return;
    const int base = nctr[8 + t];
    const int sz = nctr[9 + t] - base;
    const int start = lt * 64;

    if (tid < 64) {
        int idx = start + tid;
        int n = (idx < sz) ? nperm[base + idx] : -1;
        sVal[tid] = (n >= 0) ? 1 : 0;
        sNode[tid] = (n >= 0) ? n : 0;
    }
    __syncthreads();

    // x0[n] = sum_p ex[p][h]*vt[p][c] / (den[h]*deg); 4-wide unrolled gather
    {
        const int h = lane >> 3;
        for (int r = 0; r < 16; ++r) {
            int row = w * 16 + r;
            int n = sNode[row];
            int s = dbase[n], d = deg[n];
            const u16* vp = vts + (long)s * 128 + 2 * lane;
            const float* ep = exs + (long)s * 8 + h;
            float a0 = 0.f, a1 = 0.f, sd0 = 0.f;
            float c0 = 0.f, c1 = 0.f, sd1 = 0.f;
            int j = 0;
            for (; j + 4 <= d; j += 4) {
                unsigned p0 = *(const unsigned*)(vp + (long)(j + 0) * 128);
                unsigned p1 = *(const unsigned*)(vp + (long)(j + 1) * 128);
                unsigned p2 = *(const unsigned*)(vp + (long)(j + 2) * 128);
                unsigned p3 = *(const unsigned*)(vp + (long)(j + 3) * 128);
                float e0 = ep[(long)(j + 0) * 8];
                float e1 = ep[(long)(j + 1) * 8];
                float e2 = ep[(long)(j + 2) * 8];
                float e3 = ep[(long)(j + 3) * 8];
                a0 += e0 * b2f(p0 & 0xffffu) + e1 * b2f(p1 & 0xffffu);
                a1 += e0 * b2f(p0 >> 16) + e1 * b2f(p1 >> 16);
                sd0 += e0 + e1;
                c0 += e2 * b2f(p2 & 0xffffu) + e3 * b2f(p3 & 0xffffu);
                c1 += e2 * b2f(p2 >> 16) + e3 * b2f(p3 >> 16);
                sd1 += e2 + e3;
            }
            for (; j < d; ++j) {
                unsigned pk = *(const unsigned*)(vp + (long)j * 128);
                float e_ = ep[(long)j * 8];
                a0 += e_ * b2f(pk & 0xffffu);
                a1 += e_ * b2f(pk >> 16);
                sd0 += e_;
            }
            a0 += c0; a1 += c1; sd0 += sd1;
            float inv = (d > 0) ? 1.f / (sd0 * (float)d) : 0.f;
            unsigned packed = (unsigned)f2b(a0 * inv) | ((unsigned)f2b(a1 * inv) << 16);
            *(unsigned*)&sX0[row * 136 + 2 * lane] = packed;
        }
    }
    __syncthreads();

    // wave w: rows 16w..16w+15, all 8 col-tiles; B-frags direct from global
    f32x4 acc[8];
#pragma unroll
    for (int nt = 0; nt < 8; ++nt) {
        float bv = ba[t * CD + nt * 16 + lx];
        acc[nt] = f32x4{bv, bv, bv, bv};
    }
    const int m0 = w * 16 + lx;
    const u16* wbase = WaT + t * 16384 + lane * 8;
#pragma unroll
    for (int kk = 0; kk < 4; ++kk) {
        bhalf8 nb[8];
#pragma unroll
        for (int ct = 0; ct < 8; ++ct)
            nb[ct] = *(const bhalf8*)(wbase + ct * 2048 + kk * 512);
        bhalf8 a = *(const bhalf8*)&sX0[m0 * 136 + kk * 32 + quad * 8];
#pragma unroll
        for (int ct = 0; ct < 8; ++ct)
            acc[ct] = __builtin_amdgcn_mfma_f32_16x16x32_bf16(a, nb[ct], acc[ct], 0, 0, 0);
    }

    const float alpha = 1.f / (1.f + expf(-skip[t]));
    const float oma = 1.f - alpha;
    float g[8], be[8];
#pragma unroll
    for (int nt = 0; nt < 8; ++nt) {
        g[nt] = gamma[t * CD + nt * 16 + lx];
        be[nt] = beta[t * CD + nt * 16 + lx];
    }
#pragma unroll
    for (int reg = 0; reg < 4; ++reg) {
        int erow = w * 16 + quad * 4 + reg;
        int n = sNode[erow];
        const float* xr = x + (long)n * CD;
        float o[8];
        float s1 = 0.f, s2 = 0.f;
#pragma unroll
        for (int nt = 0; nt < 8; ++nt) {
            float xv = xr[nt * 16 + lx];
            float ov = acc[nt][reg] * alpha + xv * oma;
            o[nt] = ov;
            s1 += ov;
            s2 += ov * ov;
        }
#pragma unroll
        for (int m = 1; m < 16; m <<= 1) {
            s1 += __shfl_xor(s1, m);
            s2 += __shfl_xor(s2, m);
        }
        float mu = s1 * (1.f / 128.f);
        float var = s2 * (1.f / 128.f) - mu * mu;
        float rs = rsqrtf(var + 1e-5f);
        if (sVal[erow]) {
            float* op = out + (long)n * CD;
#pragma unroll
            for (int nt = 0; nt < 8; ++nt)
                op[nt * 16 + lx] = (o[nt] - mu) * rs * g[nt] + be[nt];
        }
    }
}

extern "C" void kernel_launch(void* const* d_in, const int* in_sizes, int n_in,
                              void* d_out, int out_size, void* d_ws, size_t ws_size,
                              hipStream_t stream) {
    const float* x        = (const float*)d_in[0];
    const int*   type_id  = (const int*)d_in[1];
    const int*   edge_idx = (const int*)d_in[2];
    const int*   edge_attr= (const int*)d_in[3];
    const float* Wk   = (const float*)d_in[4];
    const float* bk   = (const float*)d_in[5];
    const float* Wq   = (const float*)d_in[6];
    const float* bq   = (const float*)d_in[7];
    const float* Wv   = (const float*)d_in[8];
    const float* bv   = (const float*)d_in[9];
    const float* Wa   = (const float*)d_in[10];
    const float* ba   = (const float*)d_in[11];
    const float* pri  = (const float*)d_in[12];
    const float* Aatt = (const float*)d_in[13];
    const float* Amsg = (const float*)d_in[14];
    const float* skip = (const float*)d_in[15];
    const float* gam  = (const float*)d_in[16];
    const float* bet  = (const float*)d_in[17];

    char* ws = (char*)d_ws;
    u16*   WqT  = (u16*)(ws + 0);
    u16*   WkT  = (u16*)(ws + 262144);
    u16*   WvT  = (u16*)(ws + 524288);
    u16*   WaT  = (u16*)(ws + 786432);
    float* bkf  = (float*)(ws + 1048576);
    float* bvf  = (float*)(ws + 1052672);
    float* exs  = (float*)(ws + 1056768);
    u16*   vts  = (u16*)(ws + 9447424);
    int*   deg  = (int*)  (ws + 76572672);
    int*   dcur = (int*)  (ws + 76703744);
    int*   dbase= (int*)  (ws + 76834816);
    int*   eperm= (int*)  (ws + 76965888);
    int*   nperm= (int*)  (ws + 78014464);
    int*   ectr = (int*)  (ws + 78145536);
    int*   nctr = (int*)  (ws + 78145792);

    const int* src = edge_idx;
    const int* dst = edge_idx + NE;

    zero_all<<<(2 * NN + 128 + 255) / 256, 256, 0, stream>>>(deg, ectr);
    prep_weights<<<(4 * NT * CD * CD + 2 * NT * CD + 255) / 256, 256, 0, stream>>>(
        Wk, bk, Wq, Wv, bv, Wa, Aatt, Amsg, WqT, WkT, WvT, WaT, bkf, bvf);
    hists<<<NE / 256, 256, 0, stream>>>(edge_attr, type_id, dst, ectr, nctr, deg);
    scan_prefix<<<2, 1024, 0, stream>>>(deg, dbase, ectr, nctr);
    scatters<<<NE / 256 + NN / 256, 256, 0, stream>>>(edge_attr, type_id, ectr, nctr,
                                                      eperm, nperm);
    edge_kernel<<<NE / 64 + NR, 256, 0, stream>>>(x, src, dst, WqT, bq, WkT, bkf, WvT, bvf,
                                                  pri, ectr, eperm, dbase, dcur, exs, vts);
    node_kernel<<<NN / 64 + NT, 256, 0, stream>>>(x, WaT, ba, skip, gam, bet, nctr, nperm,
                                                  dbase, deg, exs, vts, (float*)d_out);
}